// Round 3
// baseline (219.206 us; speedup 1.0000x reference)
//
#include <hip/hip_runtime.h>
#include <stdint.h>

// Problem: x (32,128,8192) f32, weight (128,128,1,2) f32
// out[b,o,p] = sum_{c,k} x[b,c,2p+k] * w[o,c,k] / sqrt(128),  out (32,128,4096) f32
// GEMM: M=(b,p)=131072, N=o=128, K=(c,k)=256. Memory-bound with bf16 MFMA.
//
// R5: two kernels again (convert_w ~2us is cheap; R3/R4's per-block convert
// prologue was the regression), plus the change that actually attacks the
// ~18us gap to the BW floor: A-prefetch DISTANCE 2. B lives in LDS (filled by
// a linear 64KB global_load_lds copy of the pre-converted weights — no VALU,
// no bank conflicts by construction), so the in-order vmcnt queue carries
// ONLY A loads and the compiler can emit vmcnt(4) waits: each A tile is
// consumed ~2 iterations (~600 cyc of pack+ds_read+MFMA) after issue instead
// of ~300 (R3/R4) or ~0 (R2, where waiting on global-B drained the queue).
// kc loop unrolled x2 with statically-named abufA/abufB so all buffer indexing
// is compile-time (runtime-indexed arrays go to scratch).

typedef __attribute__((ext_vector_type(8))) short bf16x8;   // 8 bf16 = 4 VGPRs
typedef __attribute__((ext_vector_type(4))) float f32x4;    // MFMA C/D

#define CIN  128
#define DLEN 8192
#define PLEN 4096
#define COUT 128

__device__ inline unsigned short f2bf(float f) {
    unsigned u = __builtin_bit_cast(unsigned, f);
    unsigned r = u + 0x7FFFu + ((u >> 16) & 1u);
    return (unsigned short)(r >> 16);
}

// pack two fp32 -> bf16x2 (RTNE), lo = a, hi = b
__device__ inline unsigned pack_bf(float a, float b) {
    unsigned ua = __builtin_bit_cast(unsigned, a);
    unsigned ub = __builtin_bit_cast(unsigned, b);
    unsigned ra = ua + 0x7FFFu + ((ua >> 16) & 1u);
    unsigned rb = ub + 0x7FFFu + ((ub >> 16) & 1u);
    return (ra >> 16) | (rb & 0xFFFF0000u);
}

// Convert weight (o,c,1,k) f32 -> bf16 in B-fragment-major layout, scale folded in.
// W flat index = o*256 + (c*2+k) = o*256 + kk.  WB bf16 index = (kk>>3)*1024 + o*8 + (kk&7).
__global__ __launch_bounds__(256) void convert_w(const float* __restrict__ w,
                                                 unsigned short* __restrict__ wb) {
    int t  = blockIdx.x * 256 + threadIdx.x;   // 0..16383
    int o  = t >> 7;                           // 0..127
    int k0 = (t & 127) * 2;                    // even k index 0..254
    const float scale = 0.088388347648318447f; // 1/sqrt(128)
    float2 f = *(const float2*)(w + o * 256 + k0);
    unsigned v = (unsigned)f2bf(f.x * scale) | ((unsigned)f2bf(f.y * scale) << 16);
    int idx = (k0 >> 3) * 1024 + o * 8 + (k0 & 7);
    *(unsigned*)(wb + idx) = v;
}

// One block = 8 waves = 512 threads, covers 256 positions of one batch, all
// 128 outputs, K=256. Each wave: 32 consecutive positions, interleaved across
// two 16x16 M-tiles (tile0 = even offsets, tile1 = odd), so each A row load is
// one float4 covering both tiles. B (pre-converted bf16, fragment-major) is
// copied linearly into 64KB LDS via global_load_lds; 2 blocks/CU = 16 waves.
__global__ __launch_bounds__(512, 4) void conv_mfma(const float* __restrict__ x,
                                                    const unsigned short* __restrict__ wb,
                                                    float* __restrict__ out) {
    __shared__ unsigned wlds[16384];   // 64 KB, same linear layout as wb

    int lane = threadIdx.x & 63;
    int w    = threadIdx.x >> 6;      // wave 0..7

    // ---- stage B: linear 64 KB copy, 1 KB per wave-call, 8 calls/wave ----
    {
        const char* gsrc = (const char*)wb + w * 1024 + lane * 16;
        char* lbase = (char*)wlds + w * 1024;
#pragma unroll
        for (int i = 0; i < 8; ++i) {
            __builtin_amdgcn_global_load_lds(
                (const __attribute__((address_space(1))) void*)(gsrc + i * 8192),
                (__attribute__((address_space(3))) void*)(lbase + i * 8192),
                16, 0, 0);
        }
    }

    int tile = blockIdx.x;            // 0..511
    int b    = tile >> 4;             // 0..31
    int pt   = (tile & 15) * 256;     // position base of block
    int quad = lane >> 4;
    int l16  = lane & 15;
    int pbase = pt + w * 32;          // wave's 32-position strip

    // A lane base: row c = quad*4 (+jj, +16*kc), elem 2*pbase + 4*l16
    const float* xl = x + (size_t)b * ((size_t)CIN * DLEN)
                        + (size_t)(quad * 4) * DLEN + 2 * pbase + 4 * l16;
    const unsigned* bb = wlds + quad * 512 + l16 * 4;

    f32x4 acc[2][8];
#pragma unroll
    for (int mt = 0; mt < 2; ++mt)
#pragma unroll
        for (int t = 0; t < 8; ++t)
            acc[mt][t] = (f32x4)(0.0f);

    // preload A for kc=0 (abufA) and kc=1 (abufB) — complete by the barrier
    float4 abufA[4], abufB[4];
#pragma unroll
    for (int jj = 0; jj < 4; ++jj) {
        abufA[jj] = *(const float4*)(xl + (size_t)jj * DLEN);
        abufB[jj] = *(const float4*)(xl + (size_t)(16 + jj) * DLEN);
    }

    __syncthreads();   // drains global_load_lds (vmcnt) + A preloads

    // One kc phase: pack AB -> fragments, prefetch A(kc+2) into AB, B from LDS, MFMA.
#define KC_BODY(KC, AB, PF)                                                        \
    {                                                                              \
        union { bf16x8 v; unsigned uu[4]; } afr0, afr1;                            \
        _Pragma("unroll")                                                          \
        for (int jj = 0; jj < 4; ++jj) {                                           \
            afr0.uu[jj] = pack_bf(AB[jj].x, AB[jj].y);                             \
            afr1.uu[jj] = pack_bf(AB[jj].z, AB[jj].w);                             \
        }                                                                          \
        if (PF) {                                                                  \
            const float* nx = xl + (size_t)(((KC) + 2) * 16) * DLEN;               \
            _Pragma("unroll")                                                      \
            for (int jj = 0; jj < 4; ++jj)                                         \
                AB[jj] = *(const float4*)(nx + (size_t)jj * DLEN);                 \
        }                                                                          \
        const unsigned* bk = bb + (KC) * 2048;                                     \
        _Pragma("unroll")                                                          \
        for (int th = 0; th < 2; ++th) {                                           \
            union { bf16x8 v; uint4 u; } bfr[4];                                   \
            _Pragma("unroll")                                                      \
            for (int tt = 0; tt < 4; ++tt)                                         \
                bfr[tt].u = *(const uint4*)(bk + (th * 4 + tt) * 64);              \
            _Pragma("unroll")                                                      \
            for (int tt = 0; tt < 4; ++tt) {                                       \
                int t = th * 4 + tt;                                               \
                acc[0][t] = __builtin_amdgcn_mfma_f32_16x16x32_bf16(afr0.v, bfr[tt].v, acc[0][t], 0, 0, 0); \
                acc[1][t] = __builtin_amdgcn_mfma_f32_16x16x32_bf16(afr1.v, bfr[tt].v, acc[1][t], 0, 0, 0); \
            }                                                                      \
        }                                                                          \
    }

#pragma unroll 1
    for (int kc2 = 0; kc2 < 4; ++kc2) {
        int kcA = kc2 * 2;
        int kcB = kc2 * 2 + 1;
        KC_BODY(kcA, abufA, (kc2 < 3));
        KC_BODY(kcB, abufB, (kc2 < 3));
    }
#undef KC_BODY

    // Epilogue: C/D row = quad*4 + reg. tile0 reg r -> p = pbase+8q+2r,
    // tile1 -> +1. Interleave regs -> 8 consecutive positions per t.
    float* ob = out + (size_t)b * ((size_t)COUT * PLEN) + pbase + quad * 8;
#pragma unroll
    for (int t = 0; t < 8; ++t) {
        int o = t * 16 + l16;
        float* orow = ob + (size_t)o * PLEN;
        f32x4 v0 = { acc[0][t][0], acc[1][t][0], acc[0][t][1], acc[1][t][1] };
        f32x4 v1 = { acc[0][t][2], acc[1][t][2], acc[0][t][3], acc[1][t][3] };
        *(f32x4*)(orow)     = v0;
        *(f32x4*)(orow + 4) = v1;
    }
}

extern "C" void kernel_launch(void* const* d_in, const int* in_sizes, int n_in,
                              void* d_out, int out_size, void* d_ws, size_t ws_size,
                              hipStream_t stream) {
    const float* x = (const float*)d_in[0];
    const float* w = (const float*)d_in[1];
    float* out = (float*)d_out;
    unsigned short* wb = (unsigned short*)d_ws;  // 64 KB of bf16 weights

    convert_w<<<64, 256, 0, stream>>>(w, wb);
    conv_mfma<<<512, 512, 0, stream>>>(x, wb, out);
}

// Round 4
// 212.807 us; speedup vs baseline: 1.0301x; 1.0301x over previous
//
#include <hip/hip_runtime.h>
#include <stdint.h>

// Problem: x (32,128,8192) f32, weight (128,128,1,2) f32
// out[b,o,p] = sum_{c,k} x[b,c,2p+k] * w[o,c,k] / sqrt(128),  out (32,128,4096) f32
// GEMM: M=(b,p)=131072, N=o=128, K=(c,k)=256. Memory-bound with bf16 MFMA.
//
// R6 = R2 restored (session argmin, 212.4 us). Post-R3/R4/R5 evidence:
//  - 74% of dur_us is two 512 MiB harness poison fills at 85-86% of HBM peak
//    (the roofline), with +-1 us/fill run-to-run drift.
//  - conv_mfma's BW floor is ~32 us (201 MB @ 6.3 TB/s); in-flight-bytes
//    arithmetic says HBM stays saturated with this structure's 4-12
//    outstanding 1KB wave-loads, so B-on-LDS (R3/R4) and distance-2 A
//    prefetch (R5) were schedule-level changes on a BW-bound loop: all
//    measured neutral-to-negative (cf. learn_hip m131-m141).
//  - Every deviation from this 256-thread / no-LDS / no-barrier structure
//    cost 1-5 us in prologue or occupancy overhead.
//
// R2: latency-bound fix — position-interleaved M-tiles so A loads are dwordx4
// (one float4 feeds both tiles), prefetch-distance-1 on A, B single-buffered
// in 2 batches, __launch_bounds__(256,4) for full 4-waves/SIMD residency.

typedef __attribute__((ext_vector_type(8))) short bf16x8;   // 8 bf16 = 4 VGPRs
typedef __attribute__((ext_vector_type(4))) float f32x4;    // MFMA C/D

#define CIN  128
#define DLEN 8192
#define PLEN 4096
#define COUT 128

__device__ inline unsigned short f2bf(float f) {
    unsigned u = __builtin_bit_cast(unsigned, f);
    unsigned r = u + 0x7FFFu + ((u >> 16) & 1u);
    return (unsigned short)(r >> 16);
}

// pack two fp32 -> bf16x2 (RTNE), lo = a, hi = b
__device__ inline unsigned pack_bf(float a, float b) {
    unsigned ua = __builtin_bit_cast(unsigned, a);
    unsigned ub = __builtin_bit_cast(unsigned, b);
    unsigned ra = ua + 0x7FFFu + ((ua >> 16) & 1u);
    unsigned rb = ub + 0x7FFFu + ((ub >> 16) & 1u);
    return (ra >> 16) | (rb & 0xFFFF0000u);
}

// Convert weight (o,c,1,k) f32 -> bf16 in B-fragment-major layout, scale folded in.
// W flat index = o*256 + (c*2+k) = o*256 + kk.  WB bf16 index = (kk>>3)*1024 + o*8 + (kk&7).
__global__ __launch_bounds__(256) void convert_w(const float* __restrict__ w,
                                                 unsigned short* __restrict__ wb) {
    int t  = blockIdx.x * 256 + threadIdx.x;   // 0..16383
    int o  = t >> 7;                           // 0..127
    int k0 = (t & 127) * 2;                    // even k index 0..254
    const float scale = 0.088388347648318447f; // 1/sqrt(128)
    float2 f = *(const float2*)(w + o * 256 + k0);
    unsigned v = (unsigned)f2bf(f.x * scale) | ((unsigned)f2bf(f.y * scale) << 16);
    int idx = (k0 >> 3) * 1024 + o * 8 + (k0 & 7);
    *(unsigned*)(wb + idx) = v;
}

// One block = 4 waves = 256 threads, covers 128 positions of one batch, all 128
// outputs, K=256. Each wave: 32 consecutive positions, interleaved across two
// 16x16 M-tiles (tile0 = even offsets, tile1 = odd), so each A row load is one
// float4 covering both tiles. No LDS, no barriers.
__global__ __launch_bounds__(256, 4) void conv_mfma(const float* __restrict__ x,
                                                    const unsigned short* __restrict__ wb,
                                                    float* __restrict__ out) {
    int tile = blockIdx.x;            // 0..1023
    int b    = tile >> 5;
    int pt   = (tile & 31) * 128;
    int lane = threadIdx.x & 63;
    int w    = threadIdx.x >> 6;      // wave 0..3
    int quad = lane >> 4;
    int l16  = lane & 15;
    int pbase = pt + w * 32;          // wave's 32-position strip

    // A lane base: row c = quad*4 (+jj, +16*kc), elem 2*pbase + 4*l16
    const float* xl = x + (size_t)b * ((size_t)CIN * DLEN)
                        + (size_t)(quad * 4) * DLEN + 2 * pbase + 4 * l16;
    const uint32_t* bb = (const uint32_t*)wb + quad * 512 + l16 * 4;

    f32x4 acc[2][8];
#pragma unroll
    for (int mt = 0; mt < 2; ++mt)
#pragma unroll
        for (int t = 0; t < 8; ++t)
            acc[mt][t] = (f32x4)(0.0f);

    // preload kc=0 A
    float4 abuf[4];
#pragma unroll
    for (int jj = 0; jj < 4; ++jj)
        abuf[jj] = *(const float4*)(xl + (size_t)jj * DLEN);

#pragma unroll 1
    for (int kc = 0; kc < 8; ++kc) {
        // consume current A: .x/.y -> tile0 (even pos), .z/.w -> tile1 (odd pos)
        union { bf16x8 v; unsigned uu[4]; } afr0, afr1;
#pragma unroll
        for (int jj = 0; jj < 4; ++jj) {
            afr0.uu[jj] = pack_bf(abuf[jj].x, abuf[jj].y);
            afr1.uu[jj] = pack_bf(abuf[jj].z, abuf[jj].w);
        }
        // prefetch next kc A (distance 1, same regs — abuf already consumed)
        if (kc < 7) {
            const float* nx = xl + (size_t)((kc + 1) * 16) * DLEN;
#pragma unroll
            for (int jj = 0; jj < 4; ++jj)
                abuf[jj] = *(const float4*)(nx + (size_t)jj * DLEN);
        }
        // B fragments for this kc: kgroup = kc*4+quad, t-stride 64 dwords
        const uint32_t* bk = bb + kc * 2048;
#pragma unroll
        for (int th = 0; th < 2; ++th) {
            union { bf16x8 v; uint4 u; } bfr[4];
#pragma unroll
            for (int tt = 0; tt < 4; ++tt)
                bfr[tt].u = *(const uint4*)(bk + (th * 4 + tt) * 64);
#pragma unroll
            for (int tt = 0; tt < 4; ++tt) {
                int t = th * 4 + tt;
                acc[0][t] = __builtin_amdgcn_mfma_f32_16x16x32_bf16(afr0.v, bfr[tt].v, acc[0][t], 0, 0, 0);
                acc[1][t] = __builtin_amdgcn_mfma_f32_16x16x32_bf16(afr1.v, bfr[tt].v, acc[1][t], 0, 0, 0);
            }
        }
    }

    // Epilogue: C/D row = quad*4 + reg. tile0 reg r -> p = pbase+8q+2r,
    // tile1 -> +1. Interleave regs -> 8 consecutive positions per t.
    float* ob = out + (size_t)b * ((size_t)COUT * PLEN) + pbase + quad * 8;
#pragma unroll
    for (int t = 0; t < 8; ++t) {
        int o = t * 16 + l16;
        float* orow = ob + (size_t)o * PLEN;
        f32x4 v0 = { acc[0][t][0], acc[1][t][0], acc[0][t][1], acc[1][t][1] };
        f32x4 v1 = { acc[0][t][2], acc[1][t][2], acc[0][t][3], acc[1][t][3] };
        *(f32x4*)(orow)     = v0;
        *(f32x4*)(orow + 4) = v1;
    }
}

extern "C" void kernel_launch(void* const* d_in, const int* in_sizes, int n_in,
                              void* d_out, int out_size, void* d_ws, size_t ws_size,
                              hipStream_t stream) {
    const float* x = (const float*)d_in[0];
    const float* w = (const float*)d_in[1];
    float* out = (float*)d_out;
    unsigned short* wb = (unsigned short*)d_ws;  // 64 KB of bf16 weights

    convert_w<<<64, 256, 0, stream>>>(w, wb);
    conv_mfma<<<1024, 256, 0, stream>>>(x, wb, out);
}